// Round 14
// baseline (3310.625 us; speedup 1.0000x reference)
//
#include <hip/hip_runtime.h>
#include <cstdint>
#include <cstddef>

// LSTM_Generator: 3-layer LSTM (H=100) + tanh projection. B=512, T=512.
//
// R13 = R12 (validated MFMA path: fragment maps, shared k-map, fp16-W +
// h hi/lo split, absmax 1.22e-4) + k-tail optimization:
//   - MFMA covers k=0..95 only: 25 tiles x 3 kt x 2(hi/lo) = 150 MFMA/step
//     (was 200; the 4th kt was 87.5% zeros)
//   - k=96..99 contribution via v_dot2_f32_f16 on the VALU pipe (fp16 W-tail
//     registers x h-tail hi/lo pairs in a 512B LDS buffer) - overlaps MFMA
//   - per-wave B reads 8 -> 6 ds_read_b128 (+ 2 tiny b64 tail reads)
//   - tile nt=24 IS units 96..99: its h outputs route to the tail buffer
// Everything else unchanged: 8 waves, double-buffered swizzled LDS, ONE
// barrier/step, xw register prefetch.

#define HH 100
#define G4 400
#define NB 512
#define NT 512
#define NBG 32
#define NTILE 25
#define KP 128   // f16 per LDS row; 16B-block XOR swizzle (write domain u<96)

typedef _Float16 f16;
typedef _Float16 f16x2 __attribute__((ext_vector_type(2)));
typedef _Float16 f16x8 __attribute__((ext_vector_type(8)));
typedef float f32x4 __attribute__((ext_vector_type(4)));

__device__ __forceinline__ float sigm(float x) { return 1.0f / (1.0f + __expf(-x)); }
__device__ __forceinline__ float tanh_(float x) { return 1.0f - 2.0f / (__expf(2.0f * x) + 1.0f); }

__device__ __forceinline__ float fdot2_(uint32_t a, uint32_t b, float c) {
  union { uint32_t u; f16x2 h; } ua, ub;
  ua.u = a; ub.u = b;
  return __builtin_amdgcn_fdot2(ua.h, ub.h, c, false);
}

#define PIN22 __attribute__((amdgpu_flat_work_group_size(512, 512), \
                             amdgpu_waves_per_eu(2, 2)))

// swizzled f16 index in a [16][KP] buffer (u < 96)
__device__ __forceinline__ int hswz(int b2, int u) {
  return b2 * KP + ((((u >> 3) ^ (b2 & 7)) << 3) | (u & 7));
}
// block read position: j = k/8 (j in 0..11 for kt 0..2)
__device__ __forceinline__ int bswz(int b2, int j) {
  return b2 * KP + ((j ^ (b2 & 7)) << 3);
}

// ---------------- weight prep ----------------
// Shared k-map (A and B): k = kt*32 + (lane>>4)*8 + j.
// A-frag: m' = nt*16 + (lane&15); orig row = (m'&3)*100 + (m'>>2).
// bias/l0/tail tables use C/D map: m' = nt*16 + (lane>>4)*4 + r.
__global__ __launch_bounds__(256) void wprep(
    const float* __restrict__ Whh0, const float* __restrict__ Whh1,
    const float* __restrict__ Whh2, const float* __restrict__ Wih1,
    const float* __restrict__ Wih2, const float* __restrict__ b1,
    const float* __restrict__ b2, const float* __restrict__ Wih0,
    const float* __restrict__ b0,
    f16* __restrict__ wfA, f16* __restrict__ wfI,
    float* __restrict__ biasf, float* __restrict__ l0w, float* __restrict__ l0b,
    uint32_t* __restrict__ wtailA)
{
  int idx = blockIdx.x * 256 + threadIdx.x;
  if (idx < 153600) {                        // wfA [3][25][4][64][8]
    int l = idx / 51200, r = idx % 51200;
    int nt = r / 2048, r2 = r % 2048;
    int kt = r2 / 512, r3 = r2 % 512;
    int lane = r3 / 8, j = r3 % 8;
    int mp = nt * 16 + (lane & 15);
    int grow = (mp & 3) * HH + (mp >> 2);
    int k = kt * 32 + (lane >> 4) * 8 + j;
    const float* W = (l == 0) ? Whh0 : ((l == 1) ? Whh1 : Whh2);
    wfA[idx] = (k < HH) ? (f16)W[grow * HH + k] : (f16)0.0f;
    return;
  }
  idx -= 153600;
  if (idx < 102400) {                        // wfI [2][25][4][64][8]
    int l = idx / 51200, r = idx % 51200;
    int nt = r / 2048, r2 = r % 2048;
    int kt = r2 / 512, r3 = r2 % 512;
    int lane = r3 / 8, j = r3 % 8;
    int mp = nt * 16 + (lane & 15);
    int grow = (mp & 3) * HH + (mp >> 2);
    int k = kt * 32 + (lane >> 4) * 8 + j;
    const float* W = (l == 0) ? Wih1 : Wih2;
    wfI[idx] = (k < HH) ? (f16)W[grow * HH + k] : (f16)0.0f;
    return;
  }
  idx -= 102400;
  if (idx < 12800) {                         // biasf [2][25][64][4]
    int l = idx / 6400, r = idx % 6400;
    int nt = r / 256, r2 = r % 256;
    int lane = r2 / 4, rr = r2 % 4;
    int mp = nt * 16 + (lane >> 4) * 4 + rr;
    int grow = (mp & 3) * HH + (mp >> 2);
    biasf[idx] = ((l == 0) ? b1 : b2)[grow];
    return;
  }
  idx -= 12800;
  if (idx < 12800) {                         // l0w / l0b [25][64][4]
    int w = idx / 6400, r = idx % 6400;
    int nt = r / 256, r2 = r % 256;
    int lane = r2 / 4, rr = r2 % 4;
    int mp = nt * 16 + (lane >> 4) * 4 + rr;
    int grow = (mp & 3) * HH + (mp >> 2);
    if (w == 0) l0w[r] = Wih0[grow];
    else        l0b[r] = b0[grow];
    return;
  }
  idx -= 12800;
  if (idx < 38400) {                         // wtailA [3][25][64][4][2] u32
    int l = idx / 12800, rem = idx % 12800;
    int nt = rem / 512, rem2 = rem % 512;
    int lane = rem2 / 8, rem3 = rem2 % 8;
    int rr = rem3 >> 1, p = rem3 & 1;
    int mp = nt * 16 + (lane >> 4) * 4 + rr;
    int grow = (mp & 3) * HH + (mp >> 2);
    const float* W = (l == 0) ? Whh0 : ((l == 1) ? Whh1 : Whh2);
    int k0 = 96 + 2 * p;
    union { f16x2 h; uint32_t u; } c;
    c.h.x = (f16)W[grow * HH + k0];
    c.h.y = (f16)W[grow * HH + k0 + 1];
    wtailA[idx] = c.u;
  }
}

// ---------------- xw pass (unchanged from R12: full 4kt, zero-padded) ----
__global__ PIN22 void xwp(
    const float* __restrict__ hbufT,   // [bg][t][u][16]
    const f16* __restrict__ wfIl,      // [25][4][64][8]
    const float* __restrict__ biasl,   // [25][64][4]
    float* __restrict__ xwf,           // [bg][CT][25][64][4]
    int t0, int CT)
{
  const int tid = threadIdx.x;
  const int w = tid >> 6, lane = tid & 63;
  const int nblk = CT / 8;
  const int bg = blockIdx.x / nblk, ts = blockIdx.x % nblk;
  const int tb = t0 + ts * 8;
  const int br = lane & 15, lg = lane >> 4;

  __shared__ __align__(16) f16 x16[8][16 * KP];   // 32KB, swizzled

  {
    uint32_t* p = (uint32_t*)&x16[0][0];
    for (int i = tid; i < 8 * 16 * KP / 2; i += 512) p[i] = 0u;
  }
  __syncthreads();
  for (int i = tid; i < 8 * HH * 16; i += 512) {
    int t = i / 1600, r = i % 1600;
    int u = r >> 4, b2 = r & 15;
    float v = hbufT[(((size_t)bg * NT + (tb + t)) * HH + u) * 16 + b2];
    // full k domain here (u up to 99): u>>3 in 0..12; 12^7=11 < 16: in range
    x16[t][b2 * KP + ((((u >> 3) ^ (b2 & 7)) << 3) | (u & 7))] = (f16)v;
  }

  const int NS = (w == 7) ? 4 : 3;
  const int tbase = 3 * w;

  f16x8 A[4][4];
  f32x4 bias4[4];
#pragma unroll
  for (int s = 0; s < 4; ++s) {
    if (s < NS) {
      int nt = tbase + s;
#pragma unroll
      for (int kt = 0; kt < 4; ++kt)
        A[s][kt] = *(const f16x8*)(wfIl + ((nt * 4 + kt) * 64 + lane) * 8);
      bias4[s] = *(const f32x4*)(biasl + (nt * 64 + lane) * 4);
    }
  }
  __syncthreads();

  for (int t = 0; t < 8; ++t) {
    f16x8 B[4];
#pragma unroll
    for (int kt = 0; kt < 4; ++kt)
      B[kt] = *(const f16x8*)(&x16[t][br * KP + ((((kt << 2) + lg) ^ (br & 7)) << 3)]);
    const int tc = ts * 8 + t;
#pragma unroll
    for (int s = 0; s < 4; ++s) {
      if (s < NS) {
        f32x4 acc = bias4[s];
#pragma unroll
        for (int kt = 0; kt < 4; ++kt)
          acc = __builtin_amdgcn_mfma_f32_16x16x32_f16(A[s][kt], B[kt], acc, 0, 0, 0);
        int nt = tbase + s;
        *(f32x4*)(xwf + ((((size_t)bg * CT + tc) * NTILE + nt) * 64 + lane) * 4) = acc;
      }
    }
  }
}

// ---------------- recurrent kernel, layers 1/2 ----------------
__global__ PIN22 void recx(
    const float* __restrict__ xwf,
    const f16* __restrict__ wfAl,
    const uint32_t* __restrict__ wtailAl,   // [25][64][4][2] u32
    float* __restrict__ hbufT,
    float* __restrict__ cbuf,
    int t0, int CT)
{
  const int tid = threadIdx.x;
  const int w = tid >> 6, lane = tid & 63;
  const int bg = blockIdx.x;
  const int br = lane & 15, lg = lane >> 4;
  const int NS = (w == 0) ? 4 : 3;          // slots: nt = w + 8*s (0..24)

  __shared__ __align__(16) f16 hHi[2][16 * KP];   // k=0..95 region used
  __shared__ __align__(16) f16 hLo[2][16 * KP];
  __shared__ __align__(8) uint32_t hTHi[2][32];   // [16 br][2 u32] = k 96..99
  __shared__ __align__(8) uint32_t hTLo[2][32];

  {
    uint32_t* p0 = (uint32_t*)&hHi[0][0];
    uint32_t* p1 = (uint32_t*)&hLo[0][0];
    for (int i = tid; i < 2 * 16 * KP / 2; i += 512) { p0[i] = 0u; p1[i] = 0u; }
    if (tid < 64) { (&hTHi[0][0])[tid] = 0u; (&hTLo[0][0])[tid] = 0u; }
  }
  __syncthreads();
  if (t0 > 0) {
    for (int i = tid; i < HH * 16; i += 512) {
      int u = i >> 4, b2 = i & 15;
      float v = hbufT[(((size_t)bg * NT + (t0 - 1)) * HH + u) * 16 + b2];
      f16 hi = (f16)v;
      f16 lo = (f16)(v - (float)hi);
      if (u < 96) {
        hHi[0][hswz(b2, u)] = hi;
        hLo[0][hswz(b2, u)] = lo;
      } else {
        ((f16*)&hTHi[0][0])[b2 * 4 + (u - 96)] = hi;
        ((f16*)&hTLo[0][0])[b2 * 4 + (u - 96)] = lo;
      }
    }
  }

  f16x8 A[4][3];
  uint2 wt[4][4];                          // [slot][r]: 2 u32 pairs (k 96-99)
  float c[4] = {0.f, 0.f, 0.f, 0.f};
  f32x4 xwC[4], xwN[4];
#pragma unroll
  for (int s = 0; s < 4; ++s) {
    if (s < NS) {
      const int nt = w + 8 * s;
#pragma unroll
      for (int kt = 0; kt < 3; ++kt)
        A[s][kt] = *(const f16x8*)(wfAl + ((nt * 4 + kt) * 64 + lane) * 8);
#pragma unroll
      for (int r = 0; r < 4; ++r)
        wt[s][r] = ((const uint2*)wtailAl)[(nt * 64 + lane) * 4 + r];
      if (t0 > 0) c[s] = cbuf[((size_t)bg * NTILE + nt) * 64 + lane];
      xwC[s] = *(const f32x4*)(xwf + (((size_t)bg * CT * NTILE + nt) * 64 + lane) * 4);
    }
  }
  __syncthreads();

  int cur = 0;
  for (int t = 0; t < CT; ++t) {
    f16x8 Bhi[3], Blo[3];
#pragma unroll
    for (int kt = 0; kt < 3; ++kt) {
      const int pos = bswz(br, (kt << 2) + lg);
      Bhi[kt] = *(const f16x8*)(&hHi[cur][pos]);
      Blo[kt] = *(const f16x8*)(&hLo[cur][pos]);
    }
    const uint2 tHi = ((const uint2*)hTHi[cur])[br];
    const uint2 tLo = ((const uint2*)hTLo[cur])[br];
    const int tn = (t + 1 < CT) ? t + 1 : t;
#pragma unroll
    for (int s = 0; s < 4; ++s) {
      if (s < NS) {
        const int nt = w + 8 * s;
        xwN[s] = *(const f32x4*)(xwf + ((((size_t)bg * CT + tn) * NTILE + nt) * 64 + lane) * 4);
      }
    }
#pragma unroll
    for (int s = 0; s < 4; ++s) {
      if (s < NS) {
        const int nt = w + 8 * s;
        // k=96..99 tail on VALU (dot2), per C-component
        float t0v = fdot2_(wt[s][0].x, tHi.x, fdot2_(wt[s][0].y, tHi.y,
                   fdot2_(wt[s][0].x, tLo.x, fdot2_(wt[s][0].y, tLo.y, xwC[s][0]))));
        float t1v = fdot2_(wt[s][1].x, tHi.x, fdot2_(wt[s][1].y, tHi.y,
                   fdot2_(wt[s][1].x, tLo.x, fdot2_(wt[s][1].y, tLo.y, xwC[s][1]))));
        float t2v = fdot2_(wt[s][2].x, tHi.x, fdot2_(wt[s][2].y, tHi.y,
                   fdot2_(wt[s][2].x, tLo.x, fdot2_(wt[s][2].y, tLo.y, xwC[s][2]))));
        float t3v = fdot2_(wt[s][3].x, tHi.x, fdot2_(wt[s][3].y, tHi.y,
                   fdot2_(wt[s][3].x, tLo.x, fdot2_(wt[s][3].y, tLo.y, xwC[s][3]))));
        f32x4 ah = {t0v, t1v, t2v, t3v};
        f32x4 al = {0.f, 0.f, 0.f, 0.f};
#pragma unroll
        for (int kt = 0; kt < 3; ++kt) {
          ah = __builtin_amdgcn_mfma_f32_16x16x32_f16(A[s][kt], Bhi[kt], ah, 0, 0, 0);
          al = __builtin_amdgcn_mfma_f32_16x16x32_f16(A[s][kt], Blo[kt], al, 0, 0, 0);
        }
        f32x4 acc = ah + al;
        float iv = sigm(acc.x);
        float fv = sigm(acc.y);
        float gv = tanh_(acc.z);
        float ov = sigm(acc.w);
        c[s] = fv * c[s] + iv * gv;
        float hv = ov * tanh_(c[s]);
        const int u = nt * 4 + lg;
        hbufT[(((size_t)bg * NT + (t0 + t)) * HH + u) * 16 + br] = hv;
        f16 hi = (f16)hv;
        f16 lo = (f16)(hv - (float)hi);
        if (nt < 24) {
          hHi[cur ^ 1][hswz(br, u)] = hi;
          hLo[cur ^ 1][hswz(br, u)] = lo;
        } else {
          ((f16*)hTHi[cur ^ 1])[br * 4 + lg] = hi;
          ((f16*)hTLo[cur ^ 1])[br * 4 + lg] = lo;
        }
      }
    }
    __syncthreads();
#pragma unroll
    for (int s = 0; s < 4; ++s) xwC[s] = xwN[s];
    cur ^= 1;
  }
#pragma unroll
  for (int s = 0; s < 4; ++s) {
    if (s < NS) {
      const int nt = w + 8 * s;
      cbuf[((size_t)bg * NTILE + nt) * 64 + lane] = c[s];
    }
  }
}

// ---------------- layer 0 (K=1 scalar input), full T ----------------
__global__ PIN22 void rec0(
    const float* __restrict__ z,       // [NB][NT]
    const float* __restrict__ l0w,     // [25][64][4]
    const float* __restrict__ l0b,     // [25][64][4]
    const f16* __restrict__ wfA0,
    const uint32_t* __restrict__ wtailA0,
    float* __restrict__ hbufT)
{
  const int tid = threadIdx.x;
  const int w = tid >> 6, lane = tid & 63;
  const int bg = blockIdx.x;
  const int br = lane & 15, lg = lane >> 4;
  const int NS = (w == 0) ? 4 : 3;

  __shared__ __align__(16) f16 hHi[2][16 * KP];
  __shared__ __align__(16) f16 hLo[2][16 * KP];
  __shared__ __align__(8) uint32_t hTHi[2][32];
  __shared__ __align__(8) uint32_t hTLo[2][32];
  __shared__ __align__(16) float zl[NT][16];   // 32KB

  {
    uint32_t* p0 = (uint32_t*)&hHi[0][0];
    uint32_t* p1 = (uint32_t*)&hLo[0][0];
    for (int i = tid; i < 2 * 16 * KP / 2; i += 512) { p0[i] = 0u; p1[i] = 0u; }
    if (tid < 64) { (&hTHi[0][0])[tid] = 0u; (&hTLo[0][0])[tid] = 0u; }
  }
  for (int i = tid; i < 16 * NT; i += 512) {
    int j = i / NT, t = i % NT;
    zl[t][j] = z[(size_t)(bg * 16 + j) * NT + t];
  }

  f16x8 A[4][3];
  uint2 wt[4][4];
  float c[4] = {0.f, 0.f, 0.f, 0.f};
  f32x4 wv[4], bv[4];
#pragma unroll
  for (int s = 0; s < 4; ++s) {
    if (s < NS) {
      const int nt = w + 8 * s;
#pragma unroll
      for (int kt = 0; kt < 3; ++kt)
        A[s][kt] = *(const f16x8*)(wfA0 + ((nt * 4 + kt) * 64 + lane) * 8);
#pragma unroll
      for (int r = 0; r < 4; ++r)
        wt[s][r] = ((const uint2*)wtailA0)[(nt * 64 + lane) * 4 + r];
      wv[s] = *(const f32x4*)(l0w + (nt * 64 + lane) * 4);
      bv[s] = *(const f32x4*)(l0b + (nt * 64 + lane) * 4);
    }
  }
  __syncthreads();

  int cur = 0;
  for (int t = 0; t < NT; ++t) {
    f16x8 Bhi[3], Blo[3];
#pragma unroll
    for (int kt = 0; kt < 3; ++kt) {
      const int pos = bswz(br, (kt << 2) + lg);
      Bhi[kt] = *(const f16x8*)(&hHi[cur][pos]);
      Blo[kt] = *(const f16x8*)(&hLo[cur][pos]);
    }
    const uint2 tHi = ((const uint2*)hTHi[cur])[br];
    const uint2 tLo = ((const uint2*)hTLo[cur])[br];
    const float zv = zl[t][br];
#pragma unroll
    for (int s = 0; s < 4; ++s) {
      if (s < NS) {
        const int nt = w + 8 * s;
        f32x4 xc = bv[s] + wv[s] * zv;
        float t0v = fdot2_(wt[s][0].x, tHi.x, fdot2_(wt[s][0].y, tHi.y,
                   fdot2_(wt[s][0].x, tLo.x, fdot2_(wt[s][0].y, tLo.y, xc.x))));
        float t1v = fdot2_(wt[s][1].x, tHi.x, fdot2_(wt[s][1].y, tHi.y,
                   fdot2_(wt[s][1].x, tLo.x, fdot2_(wt[s][1].y, tLo.y, xc.y))));
        float t2v = fdot2_(wt[s][2].x, tHi.x, fdot2_(wt[s][2].y, tHi.y,
                   fdot2_(wt[s][2].x, tLo.x, fdot2_(wt[s][2].y, tLo.y, xc.z))));
        float t3v = fdot2_(wt[s][3].x, tHi.x, fdot2_(wt[s][3].y, tHi.y,
                   fdot2_(wt[s][3].x, tLo.x, fdot2_(wt[s][3].y, tLo.y, xc.w))));
        f32x4 ah = {t0v, t1v, t2v, t3v};
        f32x4 al = {0.f, 0.f, 0.f, 0.f};
#pragma unroll
        for (int kt = 0; kt < 3; ++kt) {
          ah = __builtin_amdgcn_mfma_f32_16x16x32_f16(A[s][kt], Bhi[kt], ah, 0, 0, 0);
          al = __builtin_amdgcn_mfma_f32_16x16x32_f16(A[s][kt], Blo[kt], al, 0, 0, 0);
        }
        f32x4 acc = ah + al;
        float iv = sigm(acc.x);
        float fv = sigm(acc.y);
        float gv = tanh_(acc.z);
        float ov = sigm(acc.w);
        c[s] = fv * c[s] + iv * gv;
        float hv = ov * tanh_(c[s]);
        const int u = nt * 4 + lg;
        hbufT[(((size_t)bg * NT + t) * HH + u) * 16 + br] = hv;
        f16 hi = (f16)hv;
        f16 lo = (f16)(hv - (float)hi);
        if (nt < 24) {
          hHi[cur ^ 1][hswz(br, u)] = hi;
          hLo[cur ^ 1][hswz(br, u)] = lo;
        } else {
          ((f16*)hTHi[cur ^ 1])[br * 4 + lg] = hi;
          ((f16*)hTLo[cur ^ 1])[br * 4 + lg] = lo;
        }
      }
    }
    __syncthreads();
    cur ^= 1;
  }
}

// ---------------- projection ----------------
__global__ __launch_bounds__(256) void proj(
    const float* __restrict__ hbufT,
    const float* __restrict__ Wp, const float* __restrict__ bp,
    float* __restrict__ out)
{
  const int tid = threadIdx.x;
  const int bg = blockIdx.x >> 5, tsub = blockIdx.x & 31;
  const int br = tid & 15, tl = tid >> 4;
  const int t = tsub * 16 + tl;
  const float* hp = hbufT + (((size_t)bg * NT + t) * HH) * 16 + br;
  float acc = 0.0f;
#pragma unroll 4
  for (int u = 0; u < HH; ++u) acc += hp[u * 16] * Wp[u];
  out[(size_t)(bg * 16 + br) * NT + t] = tanh_(acc + bp[0]);
}

extern "C" void kernel_launch(void* const* d_in, const int* in_sizes, int n_in,
                              void* d_out, int out_size, void* d_ws, size_t ws_size,
                              hipStream_t stream) {
  const float* z    = (const float*)d_in[0];
  const float* Wih0 = (const float*)d_in[1];
  const float* Whh0 = (const float*)d_in[2];
  const float* b0   = (const float*)d_in[3];
  const float* Wih1 = (const float*)d_in[4];
  const float* Whh1 = (const float*)d_in[5];
  const float* b1   = (const float*)d_in[6];
  const float* Wih2 = (const float*)d_in[7];
  const float* Whh2 = (const float*)d_in[8];
  const float* b2   = (const float*)d_in[9];
  const float* Wp   = (const float*)d_in[10];
  const float* bp   = (const float*)d_in[11];
  float* out = (float*)d_out;

  float* ws = (float*)d_ws;
  float*    hbufT  = ws;                       // [32][512][100][16]
  float*    cbuf   = ws + 26214400;            // 51,200
  f16*      wfA    = (f16*)(ws + 26265600);    // 153,600 halves
  f16*      wfI    = (f16*)(ws + 26342400);    // 102,400 halves
  float*    biasf  = ws + 26393600;            // 12,800
  float*    l0w    = ws + 26406400;            // 6,400
  float*    l0b    = ws + 26412800;            // 6,400
  uint32_t* wtailA = (uint32_t*)(ws + 26419200); // 38,400 u32
  float*    xwf    = ws + 26457600;            // [32][CT][25][64][4]

  const size_t fixed = 26457600;
  int CT = 16;
  for (int c : {128, 64, 32, 16}) {
    if ((fixed + (size_t)NBG * c * 6400) * 4 <= ws_size) { CT = c; break; }
  }

  wprep<<<1250, 256, 0, stream>>>(Whh0, Whh1, Whh2, Wih1, Wih2, b1, b2,
                                  Wih0, b0, wfA, wfI, biasf, l0w, l0b, wtailA);

  rec0<<<NBG, 512, 0, stream>>>(z, l0w, l0b, wfA, wtailA, hbufT);

  for (int l = 0; l < 2; ++l) {
    const f16* wfAl = wfA + (size_t)(l + 1) * 51200;
    const f16* wfIl = wfI + (size_t)l * 51200;
    const float* bfl = biasf + (size_t)l * 6400;
    const uint32_t* wtl = wtailA + (size_t)(l + 1) * 12800;
    for (int t0 = 0; t0 < NT; t0 += CT) {
      xwp<<<NBG * (CT / 8), 512, 0, stream>>>(hbufT, wfIl, bfl, xwf, t0, CT);
      recx<<<NBG, 512, 0, stream>>>(xwf, wfAl, wtl, hbufT, cbuf, t0, CT);
    }
  }

  proj<<<1024, 256, 0, stream>>>(hbufT, Wp, bp, out);
}

// Round 15
// 3035.325 us; speedup vs baseline: 1.0907x; 1.0907x over previous
//
#include <hip/hip_runtime.h>
#include <cstdint>
#include <cstddef>

// LSTM_Generator: 3-layer LSTM (H=100) + tanh projection. B=512, T=512.
//
// R14 = R12 (validated MFMA path: 8 waves, double-buffered swizzled LDS,
// hi/lo split, absmax 1.22e-4; R13's dot2-tail reverted -- it serialized
// before the MFMA chain) + SPLIT BARRIER:
//   __syncthreads() emits s_waitcnt vmcnt(0) lgkmcnt(0) before s_barrier,
//   draining the per-step global h-store (~500-1500 cyc) that nothing in
//   this kernel reads. Cross-round evidence: ~1.3-1.7us/step FIXED cost
//   across totally different compute bodies (R8 VALU / R12 MFMA / R13).
//   Replace in-loop syncthreads with:
//     sched_barrier(0); s_waitcnt lgkmcnt(0); s_barrier; sched_barrier(0)
//   LDS ordering preserved (lgkmcnt+barrier); stores/loads stay in flight.
//   xw prefetch loads are issued BEFORE the h-store, so the compiler's
//   counted vmcnt wait for them does not drain the younger store.

#define HH 100
#define G4 400
#define NB 512
#define NT 512
#define NBG 32
#define NTILE 25
#define KP 128   // f16 per LDS row; 16B-block XOR swizzle

typedef _Float16 f16;
typedef _Float16 f16x8 __attribute__((ext_vector_type(8)));
typedef float f32x4 __attribute__((ext_vector_type(4)));

__device__ __forceinline__ float sigm(float x) { return 1.0f / (1.0f + __expf(-x)); }
__device__ __forceinline__ float tanh_(float x) { return 1.0f - 2.0f / (__expf(2.0f * x) + 1.0f); }

#define PIN22 __attribute__((amdgpu_flat_work_group_size(512, 512), \
                             amdgpu_waves_per_eu(2, 2)))

// split barrier: order LDS, do NOT drain vmem (global stores keep flying)
__device__ __forceinline__ void lds_barrier() {
  __builtin_amdgcn_sched_barrier(0);
  asm volatile("s_waitcnt lgkmcnt(0)" ::: "memory");
  __builtin_amdgcn_s_barrier();
  __builtin_amdgcn_sched_barrier(0);
}

// swizzled f16 index in a [16][KP] buffer: batch row b2, element k=u
__device__ __forceinline__ int hswz(int b2, int u) {
  return b2 * KP + ((((u >> 3) ^ (b2 & 7)) << 3) | (u & 7));
}
// block read position: j = k/8
__device__ __forceinline__ int bswz(int b2, int j) {
  return b2 * KP + ((j ^ (b2 & 7)) << 3);
}

// ---------------- weight prep (verbatim R10/R12, validated) ----------------
__global__ __launch_bounds__(256) void wprep(
    const float* __restrict__ Whh0, const float* __restrict__ Whh1,
    const float* __restrict__ Whh2, const float* __restrict__ Wih1,
    const float* __restrict__ Wih2, const float* __restrict__ b1,
    const float* __restrict__ b2, const float* __restrict__ Wih0,
    const float* __restrict__ b0,
    f16* __restrict__ wfA, f16* __restrict__ wfI,
    float* __restrict__ biasf, float* __restrict__ l0w, float* __restrict__ l0b)
{
  int idx = blockIdx.x * 256 + threadIdx.x;
  if (idx < 153600) {                        // wfA [3][25][4][64][8]
    int l = idx / 51200, r = idx % 51200;
    int nt = r / 2048, r2 = r % 2048;
    int kt = r2 / 512, r3 = r2 % 512;
    int lane = r3 / 8, j = r3 % 8;
    int mp = nt * 16 + (lane & 15);
    int grow = (mp & 3) * HH + (mp >> 2);
    int k = kt * 32 + (lane >> 4) * 8 + j;
    const float* W = (l == 0) ? Whh0 : ((l == 1) ? Whh1 : Whh2);
    wfA[idx] = (k < HH) ? (f16)W[grow * HH + k] : (f16)0.0f;
    return;
  }
  idx -= 153600;
  if (idx < 102400) {                        // wfI [2][25][4][64][8]
    int l = idx / 51200, r = idx % 51200;
    int nt = r / 2048, r2 = r % 2048;
    int kt = r2 / 512, r3 = r2 % 512;
    int lane = r3 / 8, j = r3 % 8;
    int mp = nt * 16 + (lane & 15);
    int grow = (mp & 3) * HH + (mp >> 2);
    int k = kt * 32 + (lane >> 4) * 8 + j;
    const float* W = (l == 0) ? Wih1 : Wih2;
    wfI[idx] = (k < HH) ? (f16)W[grow * HH + k] : (f16)0.0f;
    return;
  }
  idx -= 102400;
  if (idx < 12800) {                         // biasf [2][25][64][4]
    int l = idx / 6400, r = idx % 6400;
    int nt = r / 256, r2 = r % 256;
    int lane = r2 / 4, rr = r2 % 4;
    int mp = nt * 16 + (lane >> 4) * 4 + rr;
    int grow = (mp & 3) * HH + (mp >> 2);
    biasf[idx] = ((l == 0) ? b1 : b2)[grow];
    return;
  }
  idx -= 12800;
  if (idx < 12800) {                         // l0w / l0b [25][64][4]
    int w = idx / 6400, r = idx % 6400;
    int nt = r / 256, r2 = r % 256;
    int lane = r2 / 4, rr = r2 % 4;
    int mp = nt * 16 + (lane >> 4) * 4 + rr;
    int grow = (mp & 3) * HH + (mp >> 2);
    if (w == 0) l0w[r] = Wih0[grow];
    else        l0b[r] = b0[grow];
  }
}

// ---------------- xw pass: xwf = bias + Wih . x^T (MFMA, parallel in t) ----
__global__ PIN22 void xwp(
    const float* __restrict__ hbufT,   // [bg][t][u][16]
    const f16* __restrict__ wfIl,      // [25][4][64][8]
    const float* __restrict__ biasl,   // [25][64][4]
    float* __restrict__ xwf,           // [bg][CT][25][64][4]
    int t0, int CT)
{
  const int tid = threadIdx.x;
  const int w = tid >> 6, lane = tid & 63;
  const int nblk = CT / 8;
  const int bg = blockIdx.x / nblk, ts = blockIdx.x % nblk;
  const int tb = t0 + ts * 8;
  const int br = lane & 15, lg = lane >> 4;

  __shared__ __align__(16) f16 x16[8][16 * KP];   // 32KB, swizzled

  {
    uint32_t* p = (uint32_t*)&x16[0][0];
    for (int i = tid; i < 8 * 16 * KP / 2; i += 512) p[i] = 0u;
  }
  __syncthreads();
  for (int i = tid; i < 8 * HH * 16; i += 512) {
    int t = i / 1600, r = i % 1600;
    int u = r >> 4, b2 = r & 15;
    float v = hbufT[(((size_t)bg * NT + (tb + t)) * HH + u) * 16 + b2];
    x16[t][hswz(b2, u)] = (f16)v;
  }

  const int NS = (w == 7) ? 4 : 3;
  const int tbase = 3 * w;

  f16x8 A[4][4];
  f32x4 bias4[4];
#pragma unroll
  for (int s = 0; s < 4; ++s) {
    if (s < NS) {
      int nt = tbase + s;
#pragma unroll
      for (int kt = 0; kt < 4; ++kt)
        A[s][kt] = *(const f16x8*)(wfIl + ((nt * 4 + kt) * 64 + lane) * 8);
      bias4[s] = *(const f32x4*)(biasl + (nt * 64 + lane) * 4);
    }
  }
  __syncthreads();

  for (int t = 0; t < 8; ++t) {
    f16x8 B[4];
#pragma unroll
    for (int kt = 0; kt < 4; ++kt)
      B[kt] = *(const f16x8*)(&x16[t][bswz(br, (kt << 2) + lg)]);
    const int tc = ts * 8 + t;
#pragma unroll
    for (int s = 0; s < 4; ++s) {
      if (s < NS) {
        f32x4 acc = bias4[s];
#pragma unroll
        for (int kt = 0; kt < 4; ++kt)
          acc = __builtin_amdgcn_mfma_f32_16x16x32_f16(A[s][kt], B[kt], acc, 0, 0, 0);
        int nt = tbase + s;
        *(f32x4*)(xwf + ((((size_t)bg * CT + tc) * NTILE + nt) * 64 + lane) * 4) = acc;
      }
    }
  }
}

// ---------------- recurrent kernel, layers 1/2 ----------------
__global__ PIN22 void recx(
    const float* __restrict__ xwf,
    const f16* __restrict__ wfAl,
    float* __restrict__ hbufT,
    float* __restrict__ cbuf,
    int t0, int CT)
{
  const int tid = threadIdx.x;
  const int w = tid >> 6, lane = tid & 63;
  const int bg = blockIdx.x;
  const int br = lane & 15, lg = lane >> 4;
  const int NS = (w == 0) ? 4 : 3;          // slots: nt = w + 8*s

  __shared__ __align__(16) f16 hHi[2][16 * KP];   // double-buffered, swizzled
  __shared__ __align__(16) f16 hLo[2][16 * KP];

  {
    uint32_t* p0 = (uint32_t*)&hHi[0][0];
    uint32_t* p1 = (uint32_t*)&hLo[0][0];
    for (int i = tid; i < 2 * 16 * KP / 2; i += 512) { p0[i] = 0u; p1[i] = 0u; }
  }
  __syncthreads();
  if (t0 > 0) {
    for (int i = tid; i < HH * 16; i += 512) {
      int u = i >> 4, b2 = i & 15;
      float v = hbufT[(((size_t)bg * NT + (t0 - 1)) * HH + u) * 16 + b2];
      f16 hi = (f16)v;
      hHi[0][hswz(b2, u)] = hi;
      hLo[0][hswz(b2, u)] = (f16)(v - (float)hi);
    }
  }

  f16x8 A[4][4];
  float c[4] = {0.f, 0.f, 0.f, 0.f};
  f32x4 xwC[4], xwN[4];
#pragma unroll
  for (int s = 0; s < 4; ++s) {
    if (s < NS) {
      const int nt = w + 8 * s;
#pragma unroll
      for (int kt = 0; kt < 4; ++kt)
        A[s][kt] = *(const f16x8*)(wfAl + ((nt * 4 + kt) * 64 + lane) * 8);
      if (t0 > 0) c[s] = cbuf[((size_t)bg * NTILE + nt) * 64 + lane];
      xwC[s] = *(const f32x4*)(xwf + (((size_t)bg * CT * NTILE + nt) * 64 + lane) * 4);
    }
  }
  __syncthreads();

  int cur = 0;
  for (int t = 0; t < CT; ++t) {
    f16x8 Bhi[4], Blo[4];
#pragma unroll
    for (int kt = 0; kt < 4; ++kt) {
      const int pos = bswz(br, (kt << 2) + lg);
      Bhi[kt] = *(const f16x8*)(&hHi[cur][pos]);
      Blo[kt] = *(const f16x8*)(&hLo[cur][pos]);
    }
    const int tn = (t + 1 < CT) ? t + 1 : t;   // prefetch next xw (issued
#pragma unroll                                  // BEFORE this step's store)
    for (int s = 0; s < 4; ++s) {
      if (s < NS) {
        const int nt = w + 8 * s;
        xwN[s] = *(const f32x4*)(xwf + ((((size_t)bg * CT + tn) * NTILE + nt) * 64 + lane) * 4);
      }
    }
#pragma unroll
    for (int s = 0; s < 4; ++s) {
      if (s < NS) {
        const int nt = w + 8 * s;
        f32x4 ah = xwC[s];
        f32x4 al = {0.f, 0.f, 0.f, 0.f};
#pragma unroll
        for (int kt = 0; kt < 4; ++kt) {       // two independent 4-deep chains
          ah = __builtin_amdgcn_mfma_f32_16x16x32_f16(A[s][kt], Bhi[kt], ah, 0, 0, 0);
          al = __builtin_amdgcn_mfma_f32_16x16x32_f16(A[s][kt], Blo[kt], al, 0, 0, 0);
        }
        f32x4 acc = ah + al;
        float iv = sigm(acc.x);
        float fv = sigm(acc.y);
        float gv = tanh_(acc.z);
        float ov = sigm(acc.w);
        c[s] = fv * c[s] + iv * gv;
        float hv = ov * tanh_(c[s]);
        const int u = nt * 4 + lg;
        hbufT[(((size_t)bg * NT + (t0 + t)) * HH + u) * 16 + br] = hv;
        f16 hi = (f16)hv;
        hHi[cur ^ 1][hswz(br, u)] = hi;
        hLo[cur ^ 1][hswz(br, u)] = (f16)(hv - (float)hi);
      }
    }
    lds_barrier();                             // NO vmem drain
#pragma unroll
    for (int s = 0; s < 4; ++s) xwC[s] = xwN[s];
    cur ^= 1;
  }
#pragma unroll
  for (int s = 0; s < 4; ++s) {
    if (s < NS) {
      const int nt = w + 8 * s;
      cbuf[((size_t)bg * NTILE + nt) * 64 + lane] = c[s];
    }
  }
}

// ---------------- layer 0 (K=1 scalar input), full T ----------------
__global__ PIN22 void rec0(
    const float* __restrict__ z,       // [NB][NT]
    const float* __restrict__ l0w,     // [25][64][4]
    const float* __restrict__ l0b,     // [25][64][4]
    const f16* __restrict__ wfA0,
    float* __restrict__ hbufT)
{
  const int tid = threadIdx.x;
  const int w = tid >> 6, lane = tid & 63;
  const int bg = blockIdx.x;
  const int br = lane & 15, lg = lane >> 4;
  const int NS = (w == 0) ? 4 : 3;

  __shared__ __align__(16) f16 hHi[2][16 * KP];
  __shared__ __align__(16) f16 hLo[2][16 * KP];
  __shared__ __align__(16) float zl[NT][16];   // 32KB

  {
    uint32_t* p0 = (uint32_t*)&hHi[0][0];
    uint32_t* p1 = (uint32_t*)&hLo[0][0];
    for (int i = tid; i < 2 * 16 * KP / 2; i += 512) { p0[i] = 0u; p1[i] = 0u; }
  }
  for (int i = tid; i < 16 * NT; i += 512) {
    int j = i / NT, t = i % NT;
    zl[t][j] = z[(size_t)(bg * 16 + j) * NT + t];
  }

  f16x8 A[4][4];
  float c[4] = {0.f, 0.f, 0.f, 0.f};
  f32x4 wv[4], bv[4];
#pragma unroll
  for (int s = 0; s < 4; ++s) {
    if (s < NS) {
      const int nt = w + 8 * s;
#pragma unroll
      for (int kt = 0; kt < 4; ++kt)
        A[s][kt] = *(const f16x8*)(wfA0 + ((nt * 4 + kt) * 64 + lane) * 8);
      wv[s] = *(const f32x4*)(l0w + (nt * 64 + lane) * 4);
      bv[s] = *(const f32x4*)(l0b + (nt * 64 + lane) * 4);
    }
  }
  __syncthreads();

  int cur = 0;
  for (int t = 0; t < NT; ++t) {
    f16x8 Bhi[4], Blo[4];
#pragma unroll
    for (int kt = 0; kt < 4; ++kt) {
      const int pos = bswz(br, (kt << 2) + lg);
      Bhi[kt] = *(const f16x8*)(&hHi[cur][pos]);
      Blo[kt] = *(const f16x8*)(&hLo[cur][pos]);
    }
    const float zv = zl[t][br];
#pragma unroll
    for (int s = 0; s < 4; ++s) {
      if (s < NS) {
        const int nt = w + 8 * s;
        f32x4 ah = bv[s] + wv[s] * zv;
        f32x4 al = {0.f, 0.f, 0.f, 0.f};
#pragma unroll
        for (int kt = 0; kt < 4; ++kt) {
          ah = __builtin_amdgcn_mfma_f32_16x16x32_f16(A[s][kt], Bhi[kt], ah, 0, 0, 0);
          al = __builtin_amdgcn_mfma_f32_16x16x32_f16(A[s][kt], Blo[kt], al, 0, 0, 0);
        }
        f32x4 acc = ah + al;
        float iv = sigm(acc.x);
        float fv = sigm(acc.y);
        float gv = tanh_(acc.z);
        float ov = sigm(acc.w);
        c[s] = fv * c[s] + iv * gv;
        float hv = ov * tanh_(c[s]);
        const int u = nt * 4 + lg;
        hbufT[(((size_t)bg * NT + t) * HH + u) * 16 + br] = hv;
        f16 hi = (f16)hv;
        hHi[cur ^ 1][hswz(br, u)] = hi;
        hLo[cur ^ 1][hswz(br, u)] = (f16)(hv - (float)hi);
      }
    }
    lds_barrier();                             // NO vmem drain
    cur ^= 1;
  }
}

// ---------------- projection ----------------
__global__ __launch_bounds__(256) void proj(
    const float* __restrict__ hbufT,
    const float* __restrict__ Wp, const float* __restrict__ bp,
    float* __restrict__ out)
{
  const int tid = threadIdx.x;
  const int bg = blockIdx.x >> 5, tsub = blockIdx.x & 31;
  const int br = tid & 15, tl = tid >> 4;
  const int t = tsub * 16 + tl;
  const float* hp = hbufT + (((size_t)bg * NT + t) * HH) * 16 + br;
  float acc = 0.0f;
#pragma unroll 4
  for (int u = 0; u < HH; ++u) acc += hp[u * 16] * Wp[u];
  out[(size_t)(bg * 16 + br) * NT + t] = tanh_(acc + bp[0]);
}

extern "C" void kernel_launch(void* const* d_in, const int* in_sizes, int n_in,
                              void* d_out, int out_size, void* d_ws, size_t ws_size,
                              hipStream_t stream) {
  const float* z    = (const float*)d_in[0];
  const float* Wih0 = (const float*)d_in[1];
  const float* Whh0 = (const float*)d_in[2];
  const float* b0   = (const float*)d_in[3];
  const float* Wih1 = (const float*)d_in[4];
  const float* Whh1 = (const float*)d_in[5];
  const float* b1   = (const float*)d_in[6];
  const float* Wih2 = (const float*)d_in[7];
  const float* Whh2 = (const float*)d_in[8];
  const float* b2   = (const float*)d_in[9];
  const float* Wp   = (const float*)d_in[10];
  const float* bp   = (const float*)d_in[11];
  float* out = (float*)d_out;

  float* ws = (float*)d_ws;
  float* hbufT = ws;                         // [32][512][100][16]
  float* cbuf  = ws + 26214400;              // 51,200
  f16*   wfA   = (f16*)(ws + 26265600);      // 153,600 halves
  f16*   wfI   = (f16*)(ws + 26342400);      // 102,400 halves
  float* biasf = ws + 26393600;              // 12,800
  float* l0w   = ws + 26406400;              // 6,400
  float* l0b   = ws + 26412800;              // 6,400
  float* xwf   = ws + 26419200;              // [32][CT][25][64][4]

  const size_t fixed = 26419200;
  int CT = 16;
  for (int c : {128, 64, 32, 16}) {
    if ((fixed + (size_t)NBG * c * 6400) * 4 <= ws_size) { CT = c; break; }
  }

  wprep<<<1100, 256, 0, stream>>>(Whh0, Whh1, Whh2, Wih1, Wih2, b1, b2,
                                  Wih0, b0, wfA, wfI, biasf, l0w, l0b);

  rec0<<<NBG, 512, 0, stream>>>(z, l0w, l0b, wfA, hbufT);

  for (int l = 0; l < 2; ++l) {
    const f16* wfAl = wfA + (size_t)(l + 1) * 51200;
    const f16* wfIl = wfI + (size_t)l * 51200;
    const float* bfl = biasf + (size_t)l * 6400;
    for (int t0 = 0; t0 < NT; t0 += CT) {
      xwp<<<NBG * (CT / 8), 512, 0, stream>>>(hbufT, wfIl, bfl, xwf, t0, CT);
      recx<<<NBG, 512, 0, stream>>>(xwf, wfAl, hbufT, cbuf, t0, CT);
    }
  }

  proj<<<1024, 256, 0, stream>>>(hbufT, Wp, bp, out);
}